// Round 4
// baseline (101.366 us; speedup 1.0000x reference)
//
#include <hip/hip_runtime.h>
#include <hip/hip_bf16.h>
#include <math.h>

#define N_ 8192
#define D_ 256
#define NT2 32                           // N_/256
#define NBLK2 (NT2*(NT2+1)/2)            // 528 upper-triangular 256^2 blocks

typedef __attribute__((ext_vector_type(8))) short bf16x8;
typedef __attribute__((ext_vector_type(4))) float f32x4;
typedef __attribute__((ext_vector_type(8))) unsigned short u16x8;

__device__ __forceinline__ unsigned short f2bf(float f) {
    unsigned int u = __float_as_uint(f);
    u += 0x7FFFu + ((u >> 16) & 1u);   // RNE
    return (unsigned short)(u >> 16);
}

__device__ __forceinline__ float softplus_dev(float p) {
    return log1pf(__expf(p));
}

__device__ __forceinline__ void gload_lds16(const void* g, void* l) {
    __builtin_amdgcn_global_load_lds(
        (const __attribute__((address_space(1))) unsigned int*)g,
        (__attribute__((address_space(3))) unsigned int*)l,
        16, 0, 0);
}

// ---------------------------------------------------------------------------
// Kernel A: out = x + noise*sqrt(v); sq[row] = ||x_row||^2; bf16 cast of x
// into ws; zero S2/S8. One wave per row, 4 rows per block.
// ---------------------------------------------------------------------------
template<bool WRITE_XB>
__global__ __launch_bounds__(256) void prep_kernel(
    const float* __restrict__ x, const float* __restrict__ noise,
    const float* __restrict__ phi, float* __restrict__ out,
    float* __restrict__ sq, unsigned short* __restrict__ xb,
    float* __restrict__ S2, float* __restrict__ S8)
{
    const int wave = threadIdx.x >> 6;
    const int lane = threadIdx.x & 63;
    const int row  = blockIdx.x * 4 + wave;

    const float v  = softplus_dev(phi[0]);
    const float sv = sqrtf(v);

    const int base = row * D_ + lane * 4;
    const float4 xv = *(const float4*)&x[base];
    const float4 nv = *(const float4*)&noise[base];

    float4 ov;
    ov.x = xv.x + nv.x * sv;
    ov.y = xv.y + nv.y * sv;
    ov.z = xv.z + nv.z * sv;
    ov.w = xv.w + nv.w * sv;
    *(float4*)&out[base] = ov;

    if (WRITE_XB) {
        ushort4 bv;
        bv.x = f2bf(xv.x); bv.y = f2bf(xv.y);
        bv.z = f2bf(xv.z); bv.w = f2bf(xv.w);
        *(ushort4*)&xb[base] = bv;
    }

    float s = xv.x*xv.x + xv.y*xv.y + xv.z*xv.z + xv.w*xv.w;
    #pragma unroll
    for (int off = 1; off < 64; off <<= 1)
        s += __shfl_xor(s, off, 64);

    if (lane == 0) {
        sq[row] = s;
        S2[row] = 0.0f;
        S8[row] = 0.0f;
    }
}

// ---------------------------------------------------------------------------
// Kernel B: upper-triangular 256x256 blocks of G = Xb*Xb^T.
// 512 thr / 8 waves (2x4), per-wave 128x64 out = 8x4 frags of 16x16x32 MFMA.
// BK=64, double-buffered, counted vmcnt(8) (T3/T4). XCD-chunked triangular
// block mapping (528 = 8*66). LDS: [256 lrows][8 slots of 16B], slot
// colp = col ^ (lrow&7) (2-way banks = free); gload_lds dest linear, source
// pre-swizzled (involution). Fused epilogue as before.
// ---------------------------------------------------------------------------
template<bool USE_XB>
__global__ __launch_bounds__(512, 2) void dist_kernel(
    const float* __restrict__ x, const unsigned short* __restrict__ xb,
    const float* __restrict__ sq, const float* __restrict__ phi,
    float* __restrict__ S2, float* __restrict__ S8)
{
    __shared__ unsigned short As[2][16384];   // 2 x 32KB
    __shared__ unsigned short Bs[2][16384];   // 2 x 32KB
    __shared__ float sqA[256];
    __shared__ float sqB[256];

    const int tid  = threadIdx.x;
    const int lane = tid & 63;
    const int wave = tid >> 6;

    // XCD-chunked bijective remap: 528 = 8 * 66
    const int t = (((int)blockIdx.x & 7) * 66) + ((int)blockIdx.x >> 3);

    // triangular decode: largest bi with bi*(65-bi)/2 <= t
    int bi = (int)((65.0f - sqrtf(65.0f * 65.0f - 8.0f * (float)t)) * 0.5f);
    while ((bi + 1) * (65 - (bi + 1)) / 2 <= t) ++bi;
    while (bi * (65 - bi) / 2 > t) --bi;
    const int bj = bi + (t - bi * (65 - bi) / 2);
    const int i0 = bi * 256, j0 = bj * 256;
    const bool diag = (bi == bj);

    const float v  = softplus_dev(phi[0]);
    const float c8 = -1.0f / (8.0f * v);

    if (tid < 256) sqA[tid] = sq[i0 + tid];
    else           sqB[tid - 256] = sq[j0 + tid - 256];

    const int wr = wave >> 2;       // 0..1 -> row 128-half
    const int wc = wave & 3;        // 0..3 -> col 64-quarter
    const int lr = lane & 15;
    const int lk = lane >> 4;

    f32x4 acc[8][4];
    #pragma unroll
    for (int m = 0; m < 8; ++m)
        #pragma unroll
        for (int n = 0; n < 4; ++n)
            acc[m][n] = (f32x4){0.f, 0.f, 0.f, 0.f};

    // slot s (0..2047): lrow=s>>3, colp=s&7, col=colp^(lrow&7); data =
    // row lrow, k-octet col (8 bf16) of the BK=64 chunk.
    auto stage_xb = [&](int kc, int buf) {
        #pragma unroll
        for (int it = 0; it < 4; ++it) {
            int wbase = it * 512 + wave * 64;
            int s     = wbase + lane;
            int lrow  = s >> 3, colp = s & 7;
            int col   = colp ^ (lrow & 7);
            size_t off = (size_t)kc * 64 + col * 8;
            gload_lds16(&xb[(size_t)(i0 + lrow) * D_ + off],
                        (char*)As[buf] + wbase * 16);
            gload_lds16(&xb[(size_t)(j0 + lrow) * D_ + off],
                        (char*)Bs[buf] + wbase * 16);
        }
    };
    auto stage_f32 = [&](int kc, int buf) {
        #pragma unroll
        for (int it = 0; it < 4; ++it) {
            int s    = it * 512 + tid;
            int lrow = s >> 3, colp = s & 7;
            int col  = colp ^ (lrow & 7);
            {
                const float* src = &x[(size_t)(i0 + lrow) * D_ + kc * 64 + col * 8];
                float4 f0 = *(const float4*)src;
                float4 f1 = *(const float4*)(src + 4);
                u16x8 u;
                u[0] = f2bf(f0.x); u[1] = f2bf(f0.y); u[2] = f2bf(f0.z); u[3] = f2bf(f0.w);
                u[4] = f2bf(f1.x); u[5] = f2bf(f1.y); u[6] = f2bf(f1.z); u[7] = f2bf(f1.w);
                *(u16x8*)((char*)As[buf] + s * 16) = u;
            }
            {
                const float* src = &x[(size_t)(j0 + lrow) * D_ + kc * 64 + col * 8];
                float4 f0 = *(const float4*)src;
                float4 f1 = *(const float4*)(src + 4);
                u16x8 u;
                u[0] = f2bf(f0.x); u[1] = f2bf(f0.y); u[2] = f2bf(f0.z); u[3] = f2bf(f0.w);
                u[4] = f2bf(f1.x); u[5] = f2bf(f1.y); u[6] = f2bf(f1.z); u[7] = f2bf(f1.w);
                *(u16x8*)((char*)Bs[buf] + s * 16) = u;
            }
        }
    };
    auto compute_chunk = [&](int buf) {
        #pragma unroll
        for (int half = 0; half < 2; ++half) {
            bf16x8 af[8], bv[4];
            #pragma unroll
            for (int m = 0; m < 8; ++m) {
                int R    = wr * 128 + m * 16 + lr;
                int colp = (half * 4 + lk) ^ (R & 7);
                af[m] = *(const bf16x8*)((const char*)As[buf] + R * 128 + colp * 16);
            }
            #pragma unroll
            for (int n = 0; n < 4; ++n) {
                int R    = wc * 64 + n * 16 + lr;
                int colp = (half * 4 + lk) ^ (R & 7);
                bv[n] = *(const bf16x8*)((const char*)Bs[buf] + R * 128 + colp * 16);
            }
            #pragma unroll
            for (int m = 0; m < 8; ++m)
                #pragma unroll
                for (int n = 0; n < 4; ++n)
                    acc[m][n] = __builtin_amdgcn_mfma_f32_16x16x32_bf16(
                        af[m], bv[n], acc[m][n], 0, 0, 0);
        }
    };

    if (USE_XB) {
        stage_xb(0, 0);
        #pragma unroll
        for (int c = 0; c < 4; ++c) {
            const int cur = c & 1;
            if (c < 3) {
                stage_xb(c + 1, cur ^ 1);
                asm volatile("s_waitcnt vmcnt(8)" ::: "memory");  // chunk c landed
            } else {
                asm volatile("s_waitcnt vmcnt(0)" ::: "memory");
            }
            __builtin_amdgcn_s_barrier();
            compute_chunk(cur);
            if (c < 3) __builtin_amdgcn_s_barrier();  // protect buf reuse
        }
    } else {
        for (int c = 0; c < 4; ++c) {
            __syncthreads();
            stage_f32(c, 0);
            __syncthreads();
            compute_chunk(0);
        }
    }

    // Epilogue. C frag: col = lane&15, row = (lane>>4)*4 + reg   [m89]
    float cs2[4] = {0.f, 0.f, 0.f, 0.f};
    float cs8[4] = {0.f, 0.f, 0.f, 0.f};
    #pragma unroll
    for (int m = 0; m < 8; ++m) {
        #pragma unroll
        for (int r = 0; r < 4; ++r) {
            int li = wr * 128 + m * 16 + lk * 4 + r;
            int gi = i0 + li;
            float si = sqA[li];
            float rs2 = 0.f, rs8 = 0.f;
            #pragma unroll
            for (int n = 0; n < 4; ++n) {
                int lj = wc * 64 + n * 16 + lr;
                float g = acc[m][n][r];
                float dd = si + sqB[lj] - 2.0f * g;
                dd = fmaxf(dd, 0.0f);
                if (diag && li == lj) dd = 0.0f;
                float e8 = __expf(dd * c8);
                float e4 = e8 * e8;
                float e2 = e4 * e4;      // exp(dd*c2) since c2 = 4*c8
                rs2 += e2; rs8 += e8;
                cs2[n] += e2; cs8[n] += e8;
            }
            #pragma unroll
            for (int off = 1; off < 16; off <<= 1) {
                rs2 += __shfl_xor(rs2, off, 64);
                rs8 += __shfl_xor(rs8, off, 64);
            }
            if (lr == 0) {
                atomicAdd(&S2[gi], rs2);
                atomicAdd(&S8[gi], rs8);
            }
        }
    }
    if (!diag) {   // symmetric contribution to rows j0.. via column sums
        #pragma unroll
        for (int n = 0; n < 4; ++n) {
            float v2 = cs2[n], v8 = cs8[n];
            v2 += __shfl_xor(v2, 16, 64); v2 += __shfl_xor(v2, 32, 64);
            v8 += __shfl_xor(v8, 16, 64); v8 += __shfl_xor(v8, 32, 64);
            if (lk == 0) {
                int gj = j0 + wc * 64 + n * 16 + lr;
                atomicAdd(&S2[gj], v2);
                atomicAdd(&S8[gj], v8);
            }
        }
    }
}

// ---------------------------------------------------------------------------
// Kernel C: finalize scalars. 1024 threads, one block.
// ---------------------------------------------------------------------------
__global__ __launch_bounds__(1024) void finalize_kernel(
    const float* __restrict__ S2, const float* __restrict__ S8,
    const float* __restrict__ sq, const float* __restrict__ phi,
    const float* __restrict__ priorv, float* __restrict__ outs)
{
    float l2 = 0.f, l8 = 0.f, ss = 0.f;
    for (int i = threadIdx.x; i < N_; i += 1024) {
        l2 += logf(S2[i]);
        l8 += logf(S8[i]);
        ss += sq[i];
    }
    #pragma unroll
    for (int off = 1; off < 64; off <<= 1) {
        l2 += __shfl_xor(l2, off, 64);
        l8 += __shfl_xor(l8, off, 64);
        ss += __shfl_xor(ss, off, 64);
    }
    __shared__ float r2[16], r8[16], rs[16];
    const int wave = threadIdx.x >> 6, lane = threadIdx.x & 63;
    if (lane == 0) { r2[wave] = l2; r8[wave] = l8; rs[wave] = ss; }
    __syncthreads();
    if (threadIdx.x == 0) {
        float L2 = 0.f, L8 = 0.f, SS = 0.f;
        for (int w = 0; w < 16; ++w) { L2 += r2[w]; L8 += r8[w]; SS += rs[w]; }
        float v = softplus_dev(phi[0]);
        float p = priorv[0];
        float logN = logf((float)N_);
        outs[0] = logN - L8 / (float)N_;                       // Ixt_lb
        outs[1] = logN - L2 / (float)N_;                       // Ixt
        outs[2] = (float)D_ * (0.5f * logf(p / v) + v / (2.0f * p) - 0.5f)
                  + SS / (2.0f * p * (float)N_);               // vIxt
    }
}

// ---------------------------------------------------------------------------
extern "C" void kernel_launch(void* const* d_in, const int* in_sizes, int n_in,
                              void* d_out, int out_size, void* d_ws, size_t ws_size,
                              hipStream_t stream) {
    const float* x     = (const float*)d_in[0];
    const float* noise = (const float*)d_in[1];
    const float* phi   = (const float*)d_in[2];
    const float* prior = (const float*)d_in[3];

    float* out  = (float*)d_out;
    float* scal = out + (size_t)N_ * D_;

    char* ws = (char*)d_ws;
    const size_t xb_bytes  = (size_t)N_ * D_ * sizeof(unsigned short);
    const size_t red_bytes = 3 * (size_t)N_ * sizeof(float);
    const bool useXb = ws_size >= xb_bytes + red_bytes;

    unsigned short* xb = (unsigned short*)ws;
    float* sq = useXb ? (float*)(ws + xb_bytes) : (float*)ws;
    float* S2 = sq + N_;
    float* S8 = S2 + N_;

    if (useXb)
        prep_kernel<true><<<N_ / 4, 256, 0, stream>>>(x, noise, phi, out, sq, xb, S2, S8);
    else
        prep_kernel<false><<<N_ / 4, 256, 0, stream>>>(x, noise, phi, out, sq, xb, S2, S8);

    if (useXb)
        dist_kernel<true><<<NBLK2, 512, 0, stream>>>(x, xb, sq, phi, S2, S8);
    else
        dist_kernel<false><<<NBLK2, 512, 0, stream>>>(x, xb, sq, phi, S2, S8);

    finalize_kernel<<<1, 1024, 0, stream>>>(S2, S8, sq, phi, prior, scal);
}

// Round 5
// 50.562 us; speedup vs baseline: 2.0048x; 2.0048x over previous
//
#include <hip/hip_runtime.h>
#include <hip/hip_bf16.h>
#include <math.h>

#define N_ 8192
#define D_ 256
#define NTILE 64                        // N_/128
#define NBLK (NTILE*(NTILE+1)/2)        // 2080 upper-triangular blocks

typedef __attribute__((ext_vector_type(8))) short bf16x8;
typedef __attribute__((ext_vector_type(4))) float f32x4;
typedef __attribute__((ext_vector_type(8))) unsigned short u16x8;

__device__ __forceinline__ unsigned short f2bf(float f) {
    unsigned int u = __float_as_uint(f);
    u += 0x7FFFu + ((u >> 16) & 1u);   // RNE
    return (unsigned short)(u >> 16);
}

__device__ __forceinline__ float softplus_dev(float p) {
    return log1pf(__expf(p));
}

__device__ __forceinline__ void gload_lds16(const void* g, void* l) {
    __builtin_amdgcn_global_load_lds(
        (const __attribute__((address_space(1))) unsigned int*)g,
        (__attribute__((address_space(3))) unsigned int*)l,
        16, 0, 0);
}

// ---------------------------------------------------------------------------
// Kernel A: out = x + noise*sqrt(v); sq[row] = ||x_row||^2; bf16 cast of x
// into ws; zero S2/S8. One wave per row, 4 rows per block.
// ---------------------------------------------------------------------------
template<bool WRITE_XB>
__global__ __launch_bounds__(256) void prep_kernel(
    const float* __restrict__ x, const float* __restrict__ noise,
    const float* __restrict__ phi, float* __restrict__ out,
    float* __restrict__ sq, unsigned short* __restrict__ xb,
    float* __restrict__ S2, float* __restrict__ S8)
{
    const int wave = threadIdx.x >> 6;
    const int lane = threadIdx.x & 63;
    const int row  = blockIdx.x * 4 + wave;

    const float v  = softplus_dev(phi[0]);
    const float sv = sqrtf(v);

    const int base = row * D_ + lane * 4;
    const float4 xv = *(const float4*)&x[base];
    const float4 nv = *(const float4*)&noise[base];

    float4 ov;
    ov.x = xv.x + nv.x * sv;
    ov.y = xv.y + nv.y * sv;
    ov.z = xv.z + nv.z * sv;
    ov.w = xv.w + nv.w * sv;
    *(float4*)&out[base] = ov;

    if (WRITE_XB) {
        ushort4 bv;
        bv.x = f2bf(xv.x); bv.y = f2bf(xv.y);
        bv.z = f2bf(xv.z); bv.w = f2bf(xv.w);
        *(ushort4*)&xb[base] = bv;
    }

    float s = xv.x*xv.x + xv.y*xv.y + xv.z*xv.z + xv.w*xv.w;
    #pragma unroll
    for (int off = 1; off < 64; off <<= 1)
        s += __shfl_xor(s, off, 64);

    if (lane == 0) {
        sq[row] = s;
        S2[row] = 0.0f;
        S8[row] = 0.0f;
    }
}

// ---------------------------------------------------------------------------
// Kernel B: upper-triangular 128x128 blocks of G = Xb*Xb^T.
// BK=32, 8 chunks, double-buffered, counted vmcnt (T3/T4). XCD-chunked
// triangular block remap (2080 = 8*260, bijective). LDS: paired-row XOR
// layout (2-way banks, free); gload_lds dest linear, source pre-swizzled.
// Epilogue: register sweep -> per-wave LDS-transpose reduction (no shuffle
// chains) -> one atomic per lane.
// ---------------------------------------------------------------------------
template<bool USE_XB>
__global__ __launch_bounds__(256, 4) void dist_kernel(
    const float* __restrict__ x, const unsigned short* __restrict__ xb,
    const float* __restrict__ sq, const float* __restrict__ phi,
    float* __restrict__ S2, float* __restrict__ S8)
{
    // SMEM[0..1] = A double-buffer, SMEM[2..3] = B double-buffer (8KB each).
    // After the K-loop it is reused as per-wave reduction scratch.
    __shared__ unsigned short SMEM[4][4096];
    __shared__ float sqA[128];
    __shared__ float sqB[128];

    const int tid  = threadIdx.x;
    const int lane = tid & 63;
    const int wave = tid >> 6;

    // XCD-chunked bijective remap: 2080 = 8 * 260
    const int t = (((int)blockIdx.x & 7) * 260) + ((int)blockIdx.x >> 3);

    // triangular decode: t -> (bi, bj), bj >= bi
    int bi = (int)((129.0f - sqrtf(129.0f * 129.0f - 8.0f * (float)t)) * 0.5f);
    while ((bi + 1) * (129 - (bi + 1)) / 2 <= t) ++bi;
    while (bi * (129 - bi) / 2 > t) --bi;
    const int bj = bi + (t - bi * (129 - bi) / 2);
    const int i0 = bi * 128, j0 = bj * 128;
    const bool diag = (bi == bj);

    const float v  = softplus_dev(phi[0]);
    const float c8 = -1.0f / (8.0f * v);

    if (tid < 128) sqA[tid] = sq[i0 + tid];
    else           sqB[tid - 128] = sq[j0 + tid - 128];

    const int wr = wave >> 1, wc = wave & 1;
    const int lr = lane & 15;
    const int lk = lane >> 4;

    f32x4 acc[4][4];
    #pragma unroll
    for (int m = 0; m < 4; ++m)
        #pragma unroll
        for (int n = 0; n < 4; ++n)
            acc[m][n] = (f32x4){0.f, 0.f, 0.f, 0.f};

    // slot s (0..511): lrow=s>>3, colp=s&7; col=colp^(lrow&7);
    // orig row = (lrow<<1)|(col>>2); k-octet = col&3.
    auto stage_xb = [&](int kc, int buf) {
        #pragma unroll
        for (int it = 0; it < 2; ++it) {
            int wbase = it * 256 + wave * 64;       // uniform slot base
            int s     = wbase + lane;
            int lrow  = s >> 3, colp = s & 7;
            int col   = colp ^ (lrow & 7);
            int orow  = (lrow << 1) | (col >> 2);
            int k8    = col & 3;
            size_t off = (size_t)kc * 32 + k8 * 8;
            gload_lds16(&xb[(size_t)(i0 + orow) * D_ + off],
                        (char*)SMEM[buf] + wbase * 16);
            gload_lds16(&xb[(size_t)(j0 + orow) * D_ + off],
                        (char*)SMEM[2 + buf] + wbase * 16);
        }
    };
    auto stage_f32 = [&](int kc, int buf) {
        #pragma unroll
        for (int it = 0; it < 2; ++it) {
            int s    = it * 256 + tid;
            int lrow = s >> 3, colp = s & 7;
            int col  = colp ^ (lrow & 7);
            int orow = (lrow << 1) | (col >> 2);
            int k8   = col & 3;
            {
                const float* src = &x[(size_t)(i0 + orow) * D_ + kc * 32 + k8 * 8];
                float4 f0 = *(const float4*)src;
                float4 f1 = *(const float4*)(src + 4);
                u16x8 u;
                u[0] = f2bf(f0.x); u[1] = f2bf(f0.y); u[2] = f2bf(f0.z); u[3] = f2bf(f0.w);
                u[4] = f2bf(f1.x); u[5] = f2bf(f1.y); u[6] = f2bf(f1.z); u[7] = f2bf(f1.w);
                *(u16x8*)((char*)SMEM[buf] + s * 16) = u;
            }
            {
                const float* src = &x[(size_t)(j0 + orow) * D_ + kc * 32 + k8 * 8];
                float4 f0 = *(const float4*)src;
                float4 f1 = *(const float4*)(src + 4);
                u16x8 u;
                u[0] = f2bf(f0.x); u[1] = f2bf(f0.y); u[2] = f2bf(f0.z); u[3] = f2bf(f0.w);
                u[4] = f2bf(f1.x); u[5] = f2bf(f1.y); u[6] = f2bf(f1.z); u[7] = f2bf(f1.w);
                *(u16x8*)((char*)SMEM[2 + buf] + s * 16) = u;
            }
        }
    };
    auto compute_chunk = [&](int buf) {
        bf16x8 af[4], bv[4];
        #pragma unroll
        for (int m = 0; m < 4; ++m) {
            int R    = wr * 64 + m * 16 + lr;
            int lrow = R >> 1;
            int colp = (((R & 1) << 2) | lk) ^ (lrow & 7);
            af[m] = *(const bf16x8*)((const char*)SMEM[buf] + lrow * 128 + colp * 16);
        }
        #pragma unroll
        for (int n = 0; n < 4; ++n) {
            int R    = wc * 64 + n * 16 + lr;
            int lrow = R >> 1;
            int colp = (((R & 1) << 2) | lk) ^ (lrow & 7);
            bv[n] = *(const bf16x8*)((const char*)SMEM[2 + buf] + lrow * 128 + colp * 16);
        }
        #pragma unroll
        for (int m = 0; m < 4; ++m)
            #pragma unroll
            for (int n = 0; n < 4; ++n)
                acc[m][n] = __builtin_amdgcn_mfma_f32_16x16x32_bf16(
                    af[m], bv[n], acc[m][n], 0, 0, 0);
    };

    if (USE_XB) {
        stage_xb(0, 0);
        #pragma unroll
        for (int c = 0; c < 8; ++c) {
            const int cur = c & 1;
            if (c < 7) {
                stage_xb(c + 1, cur ^ 1);
                asm volatile("s_waitcnt vmcnt(4)" ::: "memory");  // chunk c landed
            } else {
                asm volatile("s_waitcnt vmcnt(0)" ::: "memory");
            }
            __builtin_amdgcn_s_barrier();
            compute_chunk(cur);
            if (c < 7) __builtin_amdgcn_s_barrier();  // protect buf reuse
        }
    } else {
        for (int c = 0; c < 8; ++c) {
            __syncthreads();
            stage_f32(c, 0);
            __syncthreads();
            compute_chunk(0);
        }
    }

    // ---- Epilogue, phase 1: register sweep. C frag: col=lane&15,
    // row=(lane>>4)*4+reg [m89]. Partials: prs*[m][r] summed over n;
    // pcs*[n] summed over (m,r). No cross-lane ops here.
    float prs2[4][4], prs8[4][4];
    float pcs2[4] = {0.f, 0.f, 0.f, 0.f};
    float pcs8[4] = {0.f, 0.f, 0.f, 0.f};
    #pragma unroll
    for (int m = 0; m < 4; ++m) {
        #pragma unroll
        for (int r = 0; r < 4; ++r) {
            int li = wr * 64 + m * 16 + lk * 4 + r;
            float si = sqA[li];
            float a2 = 0.f, a8 = 0.f;
            #pragma unroll
            for (int n = 0; n < 4; ++n) {
                int lj = wc * 64 + n * 16 + lr;
                float g = acc[m][n][r];
                float dd = si + sqB[lj] - 2.0f * g;
                dd = fmaxf(dd, 0.0f);
                if (diag && li == lj) dd = 0.0f;
                float e8 = __expf(dd * c8);
                float e4 = e8 * e8;
                float e2 = e4 * e4;      // exp(dd*c2) since c2 = 4*c8
                a2 += e2; a8 += e8;
                pcs2[n] += e2; pcs8[n] += e8;
            }
            prs2[m][r] = a2; prs8[m][r] = a8;
        }
    }

    // ---- Phase 2: per-wave LDS transpose reduction (scratch overlays SMEM).
    __syncthreads();   // all waves done reading staging LDS
    float* scr = (float*)&SMEM[0][0] + wave * 1088;   // 64x17 f32 region

    // rows, array S2
    #pragma unroll
    for (int m = 0; m < 4; ++m)
        #pragma unroll
        for (int r = 0; r < 4; ++r)
            scr[(m * 16 + lk * 4 + r) * 17 + lr] = prs2[m][r];
    asm volatile("s_waitcnt lgkmcnt(0)" ::: "memory");
    __builtin_amdgcn_sched_barrier(0);
    {
        float s = 0.f;
        #pragma unroll
        for (int k = 0; k < 16; ++k) s += scr[lane * 17 + k];
        atomicAdd(&S2[i0 + wr * 64 + lane], s);
    }
    asm volatile("s_waitcnt lgkmcnt(0)" ::: "memory");
    __builtin_amdgcn_sched_barrier(0);

    // rows, array S8
    #pragma unroll
    for (int m = 0; m < 4; ++m)
        #pragma unroll
        for (int r = 0; r < 4; ++r)
            scr[(m * 16 + lk * 4 + r) * 17 + lr] = prs8[m][r];
    asm volatile("s_waitcnt lgkmcnt(0)" ::: "memory");
    __builtin_amdgcn_sched_barrier(0);
    {
        float s = 0.f;
        #pragma unroll
        for (int k = 0; k < 16; ++k) s += scr[lane * 17 + k];
        atomicAdd(&S8[i0 + wr * 64 + lane], s);
    }
    asm volatile("s_waitcnt lgkmcnt(0)" ::: "memory");
    __builtin_amdgcn_sched_barrier(0);

    // cols (off-diag blocks only): [64][11] region, cs2 at +lk, cs8 at +5+lk
    #pragma unroll
    for (int n = 0; n < 4; ++n) {
        int cl = n * 16 + lr;
        scr[cl * 11 + lk]     = pcs2[n];
        scr[cl * 11 + 5 + lk] = pcs8[n];
    }
    asm volatile("s_waitcnt lgkmcnt(0)" ::: "memory");
    __builtin_amdgcn_sched_barrier(0);
    if (!diag) {
        float s2c = 0.f, s8c = 0.f;
        #pragma unroll
        for (int k = 0; k < 4; ++k) {
            s2c += scr[lane * 11 + k];
            s8c += scr[lane * 11 + 5 + k];
        }
        int gj = j0 + wc * 64 + lane;
        atomicAdd(&S2[gj], s2c);
        atomicAdd(&S8[gj], s8c);
    }
}

// ---------------------------------------------------------------------------
// Kernel C: finalize scalars. 1024 threads, one block.
// ---------------------------------------------------------------------------
__global__ __launch_bounds__(1024) void finalize_kernel(
    const float* __restrict__ S2, const float* __restrict__ S8,
    const float* __restrict__ sq, const float* __restrict__ phi,
    const float* __restrict__ priorv, float* __restrict__ outs)
{
    float l2 = 0.f, l8 = 0.f, ss = 0.f;
    for (int i = threadIdx.x; i < N_; i += 1024) {
        l2 += logf(S2[i]);
        l8 += logf(S8[i]);
        ss += sq[i];
    }
    #pragma unroll
    for (int off = 1; off < 64; off <<= 1) {
        l2 += __shfl_xor(l2, off, 64);
        l8 += __shfl_xor(l8, off, 64);
        ss += __shfl_xor(ss, off, 64);
    }
    __shared__ float r2[16], r8[16], rs[16];
    const int wave = threadIdx.x >> 6, lane = threadIdx.x & 63;
    if (lane == 0) { r2[wave] = l2; r8[wave] = l8; rs[wave] = ss; }
    __syncthreads();
    if (threadIdx.x == 0) {
        float L2 = 0.f, L8 = 0.f, SS = 0.f;
        for (int w = 0; w < 16; ++w) { L2 += r2[w]; L8 += r8[w]; SS += rs[w]; }
        float v = softplus_dev(phi[0]);
        float p = priorv[0];
        float logN = logf((float)N_);
        outs[0] = logN - L8 / (float)N_;                       // Ixt_lb
        outs[1] = logN - L2 / (float)N_;                       // Ixt
        outs[2] = (float)D_ * (0.5f * logf(p / v) + v / (2.0f * p) - 0.5f)
                  + SS / (2.0f * p * (float)N_);               // vIxt
    }
}

// ---------------------------------------------------------------------------
extern "C" void kernel_launch(void* const* d_in, const int* in_sizes, int n_in,
                              void* d_out, int out_size, void* d_ws, size_t ws_size,
                              hipStream_t stream) {
    const float* x     = (const float*)d_in[0];
    const float* noise = (const float*)d_in[1];
    const float* phi   = (const float*)d_in[2];
    const float* prior = (const float*)d_in[3];

    float* out  = (float*)d_out;
    float* scal = out + (size_t)N_ * D_;

    char* ws = (char*)d_ws;
    const size_t xb_bytes  = (size_t)N_ * D_ * sizeof(unsigned short);
    const size_t red_bytes = 3 * (size_t)N_ * sizeof(float);
    const bool useXb = ws_size >= xb_bytes + red_bytes;

    unsigned short* xb = (unsigned short*)ws;
    float* sq = useXb ? (float*)(ws + xb_bytes) : (float*)ws;
    float* S2 = sq + N_;
    float* S8 = S2 + N_;

    if (useXb)
        prep_kernel<true><<<N_ / 4, 256, 0, stream>>>(x, noise, phi, out, sq, xb, S2, S8);
    else
        prep_kernel<false><<<N_ / 4, 256, 0, stream>>>(x, noise, phi, out, sq, xb, S2, S8);

    if (useXb)
        dist_kernel<true><<<NBLK, 256, 0, stream>>>(x, xb, sq, phi, S2, S8);
    else
        dist_kernel<false><<<NBLK, 256, 0, stream>>>(x, xb, sq, phi, S2, S8);

    finalize_kernel<<<1, 1024, 0, stream>>>(S2, S8, sq, phi, prior, scal);
}